// Round 6
// baseline (148.681 us; speedup 1.0000x reference)
//
#include <hip/hip_runtime.h>
#include <hip/hip_bf16.h>

#define RES 0.1f

constexpr int B_ = 512;
constexpr int N_ = 8192;        // points per batch
constexpr int H_ = 200;
constexpr int W_ = 200;
constexpr int MAP = H_ * W_;    // 40000 bf16 elems = 80,000 B per buffer
constexpr int MAPW = MAP / 2;   // 20000 dwords per buffer
constexpr long long TOTAL = (long long)B_ * N_;   // 4,194,304

constexpr int NBLK = 256;       // persistent: one block per CU
constexpr int TPB  = 1024;      // 16 waves
constexpr int PPT  = 8;         // points per thread per batch
constexpr int V4   = PPT / 2;   // float4 point loads per batch
constexpr int MV4  = 10;        // float4 map loads per thread (10*1024 >= 10000)
constexpr int BATCH = 4;

// gather + blend PPT points from a bf16 map buffer (dword view), batched for MLP
__device__ __forceinline__ float compute_batch(const float4 p[V4],
                                               const unsigned int* __restrict__ smapw)
{
    float acc = 0.0f;
    #pragma unroll
    for (int bat = 0; bat < PPT / BATCH; ++bat) {
        int   jr0[BATCH], jr1[BATCH], sel[BATCH];
        float dxA[BATCH], dyA[BATCH];
        bool  orA[BATCH];

        #pragma unroll
        for (int t = 0; t < BATCH; ++t) {
            const int pt = bat * BATCH + t;
            const float4 pv = p[pt >> 1];
            const float qx = (pt & 1) ? pv.z : pv.x;
            const float qy = (pt & 1) ? pv.w : pv.y;

            orA[t] = (qx < -9.9f) | (qx > 9.9f) | (qy < -9.9f) | (qy > 9.9f);

            float px = fminf(fmaxf(qx, -9.9f), 9.9f);
            float py = fminf(fmaxf(qy, -9.9f), 9.9f);

            float pmx = px - 0.5f * RES;
            float pmy = py - 0.5f * RES;

            int ix = (int)floorf((pmx + 10.0f) * 10.0f);
            int iy = (int)floorf((pmy + 10.0f) * 10.0f);

            float ipx = ((float)ix + 0.5f) * RES - 10.0f;
            float ipy = ((float)iy + 0.5f) * RES - 10.0f;

            dxA[t] = (px - ipx) * 10.0f;
            dyA[t] = (py - ipy) * 10.0f;

            const int base = ix * W_ + iy;
            jr0[t] = base >> 1;
            jr1[t] = (base + W_) >> 1;
            sel[t] = base & 1;
        }

        unsigned int w00[BATCH], w01[BATCH], w10[BATCH], w11[BATCH];
        #pragma unroll
        for (int t = 0; t < BATCH; ++t) {
            w00[t] = smapw[jr0[t]];
            w01[t] = smapw[jr0[t] + 1];
            w10[t] = smapw[jr1[t]];
            w11[t] = smapw[jr1[t] + 1];
        }

        #pragma unroll
        for (int t = 0; t < BATCH; ++t) {
            unsigned int c00 = sel[t] ? (w00[t] >> 16)     : (w00[t] & 0xffffu);
            unsigned int c01 = sel[t] ? (w01[t] & 0xffffu) : (w00[t] >> 16);
            unsigned int c10 = sel[t] ? (w10[t] >> 16)     : (w10[t] & 0xffffu);
            unsigned int c11 = sel[t] ? (w11[t] & 0xffffu) : (w10[t] >> 16);

            float v00 = __uint_as_float(c00 << 16);
            float v01 = __uint_as_float(c01 << 16);
            float v10 = __uint_as_float(c10 << 16);
            float v11 = __uint_as_float(c11 << 16);

            float dx = dxA[t], dy = dyA[t];
            float vx0 = (1.0f - dx) * v00 + dx * v10;
            float vx1 = (1.0f - dx) * v01 + dx * v11;
            float v   = (1.0f - dy) * vx0 + dy * vx1;

            float dists = orA[t] ? -1.0f : v;
            float viod  = 10.0f * (0.3f - dists);
            float r     = viod > 0.0f ? viod : 0.0f;
            acc += r * r;
        }
    }
    return acc;
}

__device__ __forceinline__ uint2 cvt4(float4 m)
{
    __hip_bfloat16 h0 = __float2bfloat16(m.x);
    __hip_bfloat16 h1 = __float2bfloat16(m.y);
    __hip_bfloat16 h2 = __float2bfloat16(m.z);
    __hip_bfloat16 h3 = __float2bfloat16(m.w);
    unsigned int lo = (unsigned int)*(const unsigned short*)&h0 |
                      ((unsigned int)*(const unsigned short*)&h1 << 16);
    unsigned int hi = (unsigned int)*(const unsigned short*)&h2 |
                      ((unsigned int)*(const unsigned short*)&h3 << 16);
    return make_uint2(lo, hi);
}

__global__ __launch_bounds__(TPB, 4) void collision_pipe(
    const float* __restrict__ opState,
    const float* __restrict__ envs,
    float* __restrict__ partial)
{
    // two bf16 map buffers, dword-aligned, +1 uint2 pad each (row-pair read
    // of the last cell touches dword (MAP-2+W_)/2 + 1 = 20000 < 20002)
    __shared__ uint2 bufA[MAPW / 2 + 1];
    __shared__ uint2 bufB[MAPW / 2 + 1];

    const int bid = blockIdx.x;
    const int tid = threadIdx.x;
    const int b0 = bid;           // first batch
    const int b1 = bid + NBLK;    // second batch

    // ---- stage batch 0: points + map -> bufA ----
    const float4* pts0 = (const float4*)((const float2*)opState + (long long)b0 * N_);
    float4 p0[V4];
    #pragma unroll
    for (int k = 0; k < V4; ++k)
        p0[k] = pts0[tid + k * TPB];

    {
        const float4* m4 = (const float4*)(envs + (long long)b0 * MAP);
        #pragma unroll
        for (int j = 0; j < MV4; ++j) {
            int idx = tid + j * TPB;
            if (idx < MAP / 4) bufA[idx] = cvt4(m4[idx]);
        }
    }
    __syncthreads();

    // ---- issue ALL batch-1 global loads BEFORE computing batch 0 ----
    const float4* m4b = (const float4*)(envs + (long long)b1 * MAP);
    float4 mreg[MV4];
    #pragma unroll
    for (int j = 0; j < MV4; ++j) {
        int idx = tid + j * TPB;
        mreg[j] = (idx < MAP / 4) ? m4b[idx] : make_float4(0.f, 0.f, 0.f, 0.f);
    }
    const float4* pts1 = (const float4*)((const float2*)opState + (long long)b1 * N_);
    float4 p1[V4];
    #pragma unroll
    for (int k = 0; k < V4; ++k)
        p1[k] = pts1[tid + k * TPB];

    // ---- compute batch 0 (overlaps batch-1 global loads in flight) ----
    float acc = compute_batch(p0, (const unsigned int*)bufA);

    // ---- drain batch-1 loads into bufB ----
    #pragma unroll
    for (int j = 0; j < MV4; ++j) {
        int idx = tid + j * TPB;
        if (idx < MAP / 4) bufB[idx] = cvt4(mreg[j]);
    }
    __syncthreads();

    // ---- compute batch 1 ----
    acc += compute_batch(p1, (const unsigned int*)bufB);

    // ---- block reduction ----
    #pragma unroll
    for (int off = 32; off > 0; off >>= 1)
        acc += __shfl_down(acc, off, 64);

    __shared__ float sacc[TPB / 64];
    const int lane = tid & 63;
    const int wid  = tid >> 6;
    if (lane == 0) sacc[wid] = acc;
    __syncthreads();

    if (tid == 0) {
        float s = 0.0f;
        #pragma unroll
        for (int w = 0; w < TPB / 64; ++w) s += sacc[w];
        partial[bid] = s;
    }
}

__global__ __launch_bounds__(256) void collision_final(
    const float* __restrict__ partial,
    float* __restrict__ out)
{
    float acc = partial[threadIdx.x];    // exactly 256 partials

    #pragma unroll
    for (int off = 32; off > 0; off >>= 1)
        acc += __shfl_down(acc, off, 64);

    __shared__ float sacc[4];
    const int lane = threadIdx.x & 63;
    const int wid  = threadIdx.x >> 6;
    if (lane == 0) sacc[wid] = acc;
    __syncthreads();

    if (threadIdx.x == 0) {
        float s = sacc[0] + sacc[1] + sacc[2] + sacc[3];
        out[0] = s / (float)TOTAL;
    }
}

extern "C" void kernel_launch(void* const* d_in, const int* in_sizes, int n_in,
                              void* d_out, int out_size, void* d_ws, size_t ws_size,
                              hipStream_t stream) {
    const float* opState = (const float*)d_in[0];   // (512, 8192, 2) f32
    const float* envs    = (const float*)d_in[1];   // (512, 1, 200, 200) f32
    float* out     = (float*)d_out;                 // scalar f32
    float* partial = (float*)d_ws;                  // 256 floats of scratch

    collision_pipe<<<NBLK, TPB, 0, stream>>>(opState, envs, partial);
    collision_final<<<1, 256, 0, stream>>>(partial, out);
}